// Round 1
// baseline (5027.338 us; speedup 1.0000x reference)
//
#include <hip/hip_runtime.h>
#include <hip/hip_bf16.h>

#define TPB 256

__device__ __forceinline__ float gelu_f(float x) {
  return 0.5f * x * (1.0f + erff(x * 0.70710678118654752440f));
}

__device__ __forceinline__ float block_sum_256(float v, float* sb) {
#pragma unroll
  for (int o = 1; o < 64; o <<= 1) v += __shfl_xor(v, o, 64);
  if ((threadIdx.x & 63) == 0) sb[threadIdx.x >> 6] = v;
  __syncthreads();
  float r = sb[0] + sb[1] + sb[2] + sb[3];
  __syncthreads();
  return r;
}

// ---------------- patch embed + pos emb + LN1(layer0) ----------------
__global__ __launch_bounds__(256) void embed_ln_kernel(
    const float* __restrict__ x, const float* __restrict__ cw,
    const float* __restrict__ cb, const float* __restrict__ cls,
    const float* __restrict__ pos, const float* __restrict__ g,
    const float* __restrict__ bb, float* __restrict__ tok,
    float* __restrict__ z) {
  __shared__ float sb[4];
  int r = blockIdx.x;  // 0..519  (b*65+s)
  int b = r / 65, s = r % 65;
  int d = threadIdx.x;
  float val;
  if (s == 0) {
    val = cls[d];
  } else {
    int p = s - 1, pi = p >> 3, pj = p & 7;
    const float* xb = x + b * 3072 + pi * 4 * 32 + pj * 4;
    const float* w = cw + d * 48;
    float acc = cb[d];
#pragma unroll
    for (int c = 0; c < 3; ++c)
#pragma unroll
      for (int i = 0; i < 4; ++i)
#pragma unroll
        for (int j = 0; j < 4; ++j)
          acc += xb[c * 1024 + i * 32 + j] * w[c * 16 + i * 4 + j];
    val = acc;
  }
  val += pos[s * 256 + d];
  tok[r * 256 + d] = val;
  float mean = block_sum_256(val, sb) * (1.0f / 256.0f);
  float dv = val - mean;
  float var = block_sum_256(dv * dv, sb) * (1.0f / 256.0f);
  z[r * 256 + d] = dv * rsqrtf(var + 1e-5f) * g[d] + bb[d];
}

// ---------------- generic tiled fp32 GEMM ----------------
// C(M x N) = A(M x K) @ B(K x N), B addressed as:
//   addr(d,c) = (c/bgroup)*bgstride + d*ldb + (c%bgroup)
// nsplit==1: fused epilogue (bias, act, residual) -> C
// nsplit>1 : partial per blockIdx.z -> C (treated as P buffer), no epilogue
#define BM 64
#define BN 64
#define BK 16

__global__ __launch_bounds__(256) void gemm_f32(
    const float* __restrict__ A, int lda, const float* __restrict__ B, int ldb,
    int bgroup, long long bgstride, float* __restrict__ C,
    const float* __restrict__ bias, const float* __restrict__ res, int act,
    int M, int N, int K, int nsplit) {
  __shared__ float As[BK][BM];
  __shared__ float Bs[BK][BN];
  const int tid = threadIdx.x;
  const int col0 = blockIdx.x * BN;
  const int row0 = blockIdx.y * BM;
  const int kchunk = K / nsplit;
  const int k0 = blockIdx.z * kchunk;
  const int k1 = k0 + kchunk;

  const float* Bt = B + (long long)(col0 / bgroup) * bgstride + (col0 % bgroup);

  const int aRow = tid >> 2;          // 0..63
  const int aCol = (tid & 3) << 2;    // 0,4,8,12
  const int bRow = tid >> 4;          // 0..15
  const int bCol = (tid & 15) << 2;   // 0..60
  const int tm = (tid >> 4) << 2;     // row micro-tile base
  const int tn = (tid & 15) << 2;     // col micro-tile base

  const bool aval = (row0 + aRow) < M;
  const float* Ap = A + (long long)(row0 + aRow) * lda + aCol;

  float acc[4][4] = {};

  for (int kt = k0; kt < k1; kt += BK) {
    float4 av = make_float4(0.f, 0.f, 0.f, 0.f);
    if (aval) av = *(const float4*)(Ap + kt);
    As[aCol + 0][aRow] = av.x;
    As[aCol + 1][aRow] = av.y;
    As[aCol + 2][aRow] = av.z;
    As[aCol + 3][aRow] = av.w;
    float4 bv = *(const float4*)(Bt + (long long)(kt + bRow) * ldb + bCol);
    *(float4*)&Bs[bRow][bCol] = bv;
    __syncthreads();
#pragma unroll
    for (int k = 0; k < BK; ++k) {
      float4 a4 = *(const float4*)&As[k][tm];
      float4 b4 = *(const float4*)&Bs[k][tn];
      acc[0][0] += a4.x * b4.x; acc[0][1] += a4.x * b4.y;
      acc[0][2] += a4.x * b4.z; acc[0][3] += a4.x * b4.w;
      acc[1][0] += a4.y * b4.x; acc[1][1] += a4.y * b4.y;
      acc[1][2] += a4.y * b4.z; acc[1][3] += a4.y * b4.w;
      acc[2][0] += a4.z * b4.x; acc[2][1] += a4.z * b4.y;
      acc[2][2] += a4.z * b4.z; acc[2][3] += a4.z * b4.w;
      acc[3][0] += a4.w * b4.x; acc[3][1] += a4.w * b4.y;
      acc[3][2] += a4.w * b4.z; acc[3][3] += a4.w * b4.w;
    }
    __syncthreads();
  }

  if (nsplit == 1) {
#pragma unroll
    for (int i = 0; i < 4; ++i) {
      int r = row0 + tm + i;
      if (r >= M) break;
      float4 o;
      float* op = &o.x;
#pragma unroll
      for (int j = 0; j < 4; ++j) {
        int c = col0 + tn + j;
        float v = acc[i][j];
        if (bias) v += bias[c];
        if (act) v = gelu_f(v);
        if (res) v += res[(long long)r * N + c];
        op[j] = v;
      }
      *(float4*)&C[(long long)r * N + col0 + tn] = o;
    }
  } else {
    float* P = C + (long long)blockIdx.z * M * N;
#pragma unroll
    for (int i = 0; i < 4; ++i) {
      int r = row0 + tm + i;
      if (r >= M) break;
      float4 o = make_float4(acc[i][0], acc[i][1], acc[i][2], acc[i][3]);
      *(float4*)&P[(long long)r * N + col0 + tn] = o;
    }
  }
}

// ---------------- split-K reduce + bias + act + residual (+ fused LN) -----
__global__ __launch_bounds__(256) void epilogue_kernel(
    const float* __restrict__ P, int nsplit, int M, int N,
    const float* __restrict__ bias, const float* __restrict__ res,
    float* __restrict__ out, int act, const float* __restrict__ g,
    const float* __restrict__ bln, float* __restrict__ z) {
  __shared__ float sb[4];
  int r = blockIdx.x;
  float myval = 0.f;
  for (int c = threadIdx.x; c < N; c += 256) {
    float acc = 0.f;
    for (int s = 0; s < nsplit; ++s)
      acc += P[(long long)s * M * N + (long long)r * N + c];
    acc += bias[c];
    if (act) acc = gelu_f(acc);
    if (res) acc += res[(long long)r * N + c];
    out[(long long)r * N + c] = acc;
    myval = acc;
  }
  if (z) {  // only used when N==256
    float mean = block_sum_256(myval, sb) * (1.f / 256.f);
    float dv = myval - mean;
    float var = block_sum_256(dv * dv, sb) * (1.f / 256.f);
    z[r * 256 + threadIdx.x] =
        dv * rsqrtf(var + 1e-5f) * g[threadIdx.x] + bln[threadIdx.x];
  }
}

// ---------------- attention: per (b,h), 17 query rows per block -----------
#define AROWS 17
__global__ __launch_bounds__(256) void attn_kernel(const float* __restrict__ qkv,
                                                   float* __restrict__ O) {
  __shared__ float qs[AROWS + 1][256];
  __shared__ float Ks[68][68];
  __shared__ float ps[AROWS][66];
  const int tid = threadIdx.x;
  const int s0 = blockIdx.x * AROWS;
  const int bh = blockIdx.y;
  const int b = bh >> 4, h = bh & 15;
  const long long base = (long long)(b * 65) * 12288 + h * 768;

  // stage Q rows
#pragma unroll
  for (int i = 0; i < AROWS; ++i) {
    int s = s0 + i;
    qs[i][tid] = (s < 65) ? qkv[base + (long long)s * 12288 + tid] : 0.f;
  }

  // scores: units = 9 i-pairs x 17 t-groups = 153
  const int up = tid / 17, tg = tid % 17;
  const int i0 = up * 2, t0 = tg * 4;
  const bool uval = (tid < 153);
  float acc[2][4] = {};
  for (int dc = 0; dc < 256; dc += 64) {
    __syncthreads();
    for (int idx = tid; idx < 65 * 64; idx += 256) {
      int t = idx >> 6, dd = idx & 63;
      Ks[t][dd] = qkv[base + (long long)t * 12288 + 256 + dc + dd];
    }
    __syncthreads();
    if (uval) {
#pragma unroll
      for (int d4 = 0; d4 < 64; d4 += 4) {
        float4 qa = *(const float4*)&qs[i0][dc + d4];
        float4 qb = *(const float4*)&qs[i0 + 1][dc + d4];
#pragma unroll
        for (int c = 0; c < 4; ++c) {
          float4 kv = *(const float4*)&Ks[t0 + c][d4];
          acc[0][c] += qa.x * kv.x + qa.y * kv.y + qa.z * kv.z + qa.w * kv.w;
          acc[1][c] += qb.x * kv.x + qb.y * kv.y + qb.z * kv.z + qb.w * kv.w;
        }
      }
    }
  }
  if (uval) {
#pragma unroll
    for (int ii = 0; ii < 2; ++ii) {
      int i = i0 + ii;
      if (i < AROWS && (s0 + i) < 65) {
#pragma unroll
        for (int c = 0; c < 4; ++c) {
          int t = t0 + c;
          if (t < 65) ps[i][t] = acc[ii][c] * 0.25f;
        }
      }
    }
  }
  __syncthreads();

  // softmax per row
  if (tid < AROWS && (s0 + tid) < 65) {
    float* row = ps[tid];
    float m = row[0];
    for (int t = 1; t < 65; ++t) m = fmaxf(m, row[t]);
    float sum = 0.f;
    for (int t = 0; t < 65; ++t) {
      float e = expf(row[t] - m);
      row[t] = e;
      sum += e;
    }
    float inv = 1.f / sum;
    for (int t = 0; t < 65; ++t) row[t] *= inv;
  }
  __syncthreads();

  // PV: thread owns column d=tid for all rows
  float oacc[AROWS];
#pragma unroll
  for (int i = 0; i < AROWS; ++i) oacc[i] = 0.f;
  const float* vp = qkv + base + 512 + tid;
  for (int t = 0; t < 65; ++t) {
    float vtd = vp[(long long)t * 12288];
#pragma unroll
    for (int i = 0; i < AROWS; ++i) oacc[i] += ps[i][t] * vtd;
  }
#pragma unroll
  for (int i = 0; i < AROWS; ++i) {
    int s = s0 + i;
    if (s < 65)
      O[(long long)(b * 65 + s) * 4096 + h * 256 + tid] = oacc[i];
  }
}

// ---------------- tiny head GEMMs ----------------
__global__ void head_gemm(const float* __restrict__ A, int lda,
                          const float* __restrict__ B,
                          const float* __restrict__ bias, float* __restrict__ C,
                          int M, int N, int K, int act) {
  int idx = blockIdx.x * 256 + threadIdx.x;
  if (idx >= M * N) return;
  int r = idx / N, c = idx % N;
  const float* a = A + (long long)r * lda;
  float acc = bias[c];
  for (int k = 0; k < K; ++k) acc += a[k] * B[(long long)k * N + c];
  if (act) acc = gelu_f(acc);
  C[(long long)r * N + c] = acc;
}

extern "C" void kernel_launch(void* const* d_in, const int* in_sizes, int n_in,
                              void* d_out, int out_size, void* d_ws,
                              size_t ws_size, hipStream_t stream) {
  const float* x = (const float*)d_in[0];
  const float* conv_w = (const float*)d_in[1];
  const float* conv_b = (const float*)d_in[2];
  const float* cls = (const float*)d_in[3];
  const float* pos = (const float*)d_in[4];
  const float* Wqkv = (const float*)d_in[5];
  const float* bqkv = (const float*)d_in[6];
  const float* Wo = (const float*)d_in[7];
  const float* bo = (const float*)d_in[8];
  const float* ln1g = (const float*)d_in[9];
  const float* ln1b = (const float*)d_in[10];
  const float* ln2g = (const float*)d_in[11];
  const float* ln2b = (const float*)d_in[12];
  const float* Wm1 = (const float*)d_in[13];
  const float* bm1 = (const float*)d_in[14];
  const float* Wm2 = (const float*)d_in[15];
  const float* bm2 = (const float*)d_in[16];
  const float* Wh1 = (const float*)d_in[17];
  const float* bh1 = (const float*)d_in[18];
  const float* Wh2 = (const float*)d_in[19];
  const float* bh2 = (const float*)d_in[20];
  const float* Wh3 = (const float*)d_in[21];
  const float* bh3 = (const float*)d_in[22];
  float* out = (float*)d_out;

  float* ws = (float*)d_ws;
  float* tok = ws;                      // 520*256
  float* z = tok + 133120;              // 520*256
  float* y1 = z + 133120;               // 520*256
  float* qkvb = y1 + 133120;            // 520*12288
  float* Ob = qkvb + 6389760;           // 520*4096
  float* h1 = Ob + 2129920;             // 520*1024
  float* Pb = h1 + 532480;              // up to 16*520*256 / 4*520*1024
  float* h2 = Pb + 2129920;             // 8*256

  const int M = 520;

  embed_ln_kernel<<<520, 256, 0, stream>>>(x, conv_w, conv_b, cls, pos, ln1g,
                                           ln1b, tok, z);

  for (int l = 0; l < 24; ++l) {
    const float* Wq = Wqkv + (long long)l * 16 * 256 * 768;
    const float* bq = bqkv + l * 12288;
    const float* Wol = Wo + (long long)l * 4096 * 256;
    const float* bol = bo + l * 256;
    const float* W1 = Wm1 + (long long)l * 256 * 1024;
    const float* b1 = bm1 + l * 1024;
    const float* W2 = Wm2 + (long long)l * 1024 * 256;
    const float* b2 = bm2 + l * 256;

    // QKV: z(520x256) @ Wqkv_l -> qkvb(520x12288), head-grouped B
    gemm_f32<<<dim3(192, 9, 1), 256, 0, stream>>>(
        z, 256, Wq, 768, 768, 196608LL, qkvb, bq, nullptr, 0, M, 12288, 256, 1);

    // attention
    attn_kernel<<<dim3(4, 128), 256, 0, stream>>>(qkvb, Ob);

    // Wo: O(520x4096) @ Wo_l(4096x256), split-K=16 -> partials
    gemm_f32<<<dim3(4, 9, 16), 256, 0, stream>>>(
        Ob, 4096, Wol, 256, 1 << 30, 0LL, Pb, nullptr, nullptr, 0, M, 256,
        4096, 16);
    // y1 = sum + bo + tok ; z = LN2(y1)
    epilogue_kernel<<<520, 256, 0, stream>>>(Pb, 16, M, 256, bol, tok, y1, 0,
                                             ln2g + l * 256, ln2b + l * 256, z);

    // MLP1: z(520x256) @ W1(256x1024), split-K=4, gelu
    gemm_f32<<<dim3(16, 9, 4), 256, 0, stream>>>(
        z, 256, W1, 1024, 1 << 30, 0LL, Pb, nullptr, nullptr, 0, M, 1024, 256,
        4);
    epilogue_kernel<<<520, 256, 0, stream>>>(Pb, 4, M, 1024, b1, nullptr, h1, 1,
                                             nullptr, nullptr, nullptr);

    // MLP2: h1(520x1024) @ W2(1024x256), split-K=8, gelu, +y1 -> tok (new carry)
    gemm_f32<<<dim3(4, 9, 8), 256, 0, stream>>>(
        h1, 1024, W2, 256, 1 << 30, 0LL, Pb, nullptr, nullptr, 0, M, 256, 1024,
        8);
    const float* ng = (l < 23) ? ln1g + (l + 1) * 256 : nullptr;
    const float* nb = (l < 23) ? ln1b + (l + 1) * 256 : nullptr;
    float* nz = (l < 23) ? z : nullptr;
    epilogue_kernel<<<520, 256, 0, stream>>>(Pb, 8, M, 256, b2, y1, tok, 1, ng,
                                             nb, nz);
  }

  // classification head on cls token (row stride 65*256 picks s==0)
  head_gemm<<<32, 256, 0, stream>>>(tok, 16640, Wh1, bh1, h1, 8, 1024, 256, 1);
  head_gemm<<<8, 256, 0, stream>>>(h1, 1024, Wh2, bh2, h2, 8, 256, 1024, 1);
  head_gemm<<<(8 * 1000 + 255) / 256, 256, 0, stream>>>(h2, 256, Wh3, bh3, out,
                                                        8, 1000, 256, 0);
}

// Round 2
// 4506.147 us; speedup vs baseline: 1.1157x; 1.1157x over previous
//
#include <hip/hip_runtime.h>
#include <hip/hip_bf16.h>

#define TPB 256

__device__ __forceinline__ float gelu_f(float x) {
  return 0.5f * x * (1.0f + erff(x * 0.70710678118654752440f));
}

__device__ __forceinline__ float block_sum_256(float v, float* sb) {
#pragma unroll
  for (int o = 1; o < 64; o <<= 1) v += __shfl_xor(v, o, 64);
  if ((threadIdx.x & 63) == 0) sb[threadIdx.x >> 6] = v;
  __syncthreads();
  float r = sb[0] + sb[1] + sb[2] + sb[3];
  __syncthreads();
  return r;
}

// ---------------- patch embed + pos emb + LN1(layer0) ----------------
__global__ __launch_bounds__(256) void embed_ln_kernel(
    const float* __restrict__ x, const float* __restrict__ cw,
    const float* __restrict__ cb, const float* __restrict__ cls,
    const float* __restrict__ pos, const float* __restrict__ g,
    const float* __restrict__ bb, float* __restrict__ tok,
    float* __restrict__ z) {
  __shared__ float sb[4];
  int r = blockIdx.x;  // 0..519  (b*65+s)
  int b = r / 65, s = r % 65;
  int d = threadIdx.x;
  float val;
  if (s == 0) {
    val = cls[d];
  } else {
    int p = s - 1, pi = p >> 3, pj = p & 7;
    const float* xb = x + b * 3072 + pi * 4 * 32 + pj * 4;
    const float* w = cw + d * 48;
    float acc = cb[d];
#pragma unroll
    for (int c = 0; c < 3; ++c)
#pragma unroll
      for (int i = 0; i < 4; ++i)
#pragma unroll
        for (int j = 0; j < 4; ++j)
          acc += xb[c * 1024 + i * 32 + j] * w[c * 16 + i * 4 + j];
    val = acc;
  }
  val += pos[s * 256 + d];
  tok[r * 256 + d] = val;
  float mean = block_sum_256(val, sb) * (1.0f / 256.0f);
  float dv = val - mean;
  float var = block_sum_256(dv * dv, sb) * (1.0f / 256.0f);
  z[r * 256 + d] = dv * rsqrtf(var + 1e-5f) * g[d] + bb[d];
}

// ---------------- generic tiled fp32 GEMM ----------------
#define BM 64
#define BN 64
#define BK 16

__global__ __launch_bounds__(256) void gemm_f32(
    const float* __restrict__ A, int lda, const float* __restrict__ B, int ldb,
    int bgroup, long long bgstride, float* __restrict__ C,
    const float* __restrict__ bias, const float* __restrict__ res, int act,
    int M, int N, int K, int nsplit) {
  __shared__ float As[BK][BM];
  __shared__ float Bs[BK][BN];
  const int tid = threadIdx.x;
  const int col0 = blockIdx.x * BN;
  const int row0 = blockIdx.y * BM;
  const int kchunk = K / nsplit;
  const int k0 = blockIdx.z * kchunk;
  const int k1 = k0 + kchunk;

  const float* Bt = B + (long long)(col0 / bgroup) * bgstride + (col0 % bgroup);

  const int aRow = tid >> 2;          // 0..63
  const int aCol = (tid & 3) << 2;    // 0,4,8,12
  const int bRow = tid >> 4;          // 0..15
  const int bCol = (tid & 15) << 2;   // 0..60
  const int tm = (tid >> 4) << 2;     // row micro-tile base
  const int tn = (tid & 15) << 2;     // col micro-tile base

  const bool aval = (row0 + aRow) < M;
  const float* Ap = A + (long long)(row0 + aRow) * lda + aCol;

  float acc[4][4] = {};

  for (int kt = k0; kt < k1; kt += BK) {
    float4 av = make_float4(0.f, 0.f, 0.f, 0.f);
    if (aval) av = *(const float4*)(Ap + kt);
    As[aCol + 0][aRow] = av.x;
    As[aCol + 1][aRow] = av.y;
    As[aCol + 2][aRow] = av.z;
    As[aCol + 3][aRow] = av.w;
    float4 bv = *(const float4*)(Bt + (long long)(kt + bRow) * ldb + bCol);
    *(float4*)&Bs[bRow][bCol] = bv;
    __syncthreads();
#pragma unroll
    for (int k = 0; k < BK; ++k) {
      float4 a4 = *(const float4*)&As[k][tm];
      float4 b4 = *(const float4*)&Bs[k][tn];
      acc[0][0] += a4.x * b4.x; acc[0][1] += a4.x * b4.y;
      acc[0][2] += a4.x * b4.z; acc[0][3] += a4.x * b4.w;
      acc[1][0] += a4.y * b4.x; acc[1][1] += a4.y * b4.y;
      acc[1][2] += a4.y * b4.z; acc[1][3] += a4.y * b4.w;
      acc[2][0] += a4.z * b4.x; acc[2][1] += a4.z * b4.y;
      acc[2][2] += a4.z * b4.z; acc[2][3] += a4.z * b4.w;
      acc[3][0] += a4.w * b4.x; acc[3][1] += a4.w * b4.y;
      acc[3][2] += a4.w * b4.z; acc[3][3] += a4.w * b4.w;
    }
    __syncthreads();
  }

  if (nsplit == 1) {
#pragma unroll
    for (int i = 0; i < 4; ++i) {
      int r = row0 + tm + i;
      if (r >= M) break;
      float4 o;
      float* op = &o.x;
#pragma unroll
      for (int j = 0; j < 4; ++j) {
        int c = col0 + tn + j;
        float v = acc[i][j];
        if (bias) v += bias[c];
        if (act) v = gelu_f(v);
        if (res) v += res[(long long)r * N + c];
        op[j] = v;
      }
      *(float4*)&C[(long long)r * N + col0 + tn] = o;
    }
  } else {
    float* P = C + (long long)blockIdx.z * M * N;
#pragma unroll
    for (int i = 0; i < 4; ++i) {
      int r = row0 + tm + i;
      if (r >= M) break;
      float4 o = make_float4(acc[i][0], acc[i][1], acc[i][2], acc[i][3]);
      *(float4*)&P[(long long)r * N + col0 + tn] = o;
    }
  }
}

// ---------------- split-K reduce + bias + act + residual (+ fused LN) -----
__global__ __launch_bounds__(256) void epilogue_kernel(
    const float* __restrict__ P, int nsplit, int M, int N,
    const float* __restrict__ bias, const float* __restrict__ res,
    float* __restrict__ out, int act, const float* __restrict__ g,
    const float* __restrict__ bln, float* __restrict__ z) {
  __shared__ float sb[4];
  int r = blockIdx.x;
  float myval = 0.f;
  for (int c = threadIdx.x; c < N; c += 256) {
    float acc = 0.f;
    for (int s = 0; s < nsplit; ++s)
      acc += P[(long long)s * M * N + (long long)r * N + c];
    acc += bias[c];
    if (act) acc = gelu_f(acc);
    if (res) acc += res[(long long)r * N + c];
    out[(long long)r * N + c] = acc;
    myval = acc;
  }
  if (z) {  // only used when N==256
    float mean = block_sum_256(myval, sb) * (1.f / 256.f);
    float dv = myval - mean;
    float var = block_sum_256(dv * dv, sb) * (1.f / 256.f);
    z[r * 256 + threadIdx.x] =
        dv * rsqrtf(var + 1e-5f) * g[threadIdx.x] + bln[threadIdx.x];
  }
}

// ---------------- attention: per (b,h), 17 query rows per block -----------
#define AROWS 17
__global__ __launch_bounds__(256) void attn_kernel(const float* __restrict__ qkv,
                                                   float* __restrict__ O) {
  __shared__ float qs[AROWS + 1][256];
  __shared__ float Ks[68][68];
  __shared__ float ps[AROWS][66];
  const int tid = threadIdx.x;
  const int s0 = blockIdx.x * AROWS;
  const int bh = blockIdx.y;
  const int b = bh >> 4, h = bh & 15;
  const long long base = (long long)(b * 65) * 12288 + h * 768;

  // stage Q rows
#pragma unroll
  for (int i = 0; i < AROWS; ++i) {
    int s = s0 + i;
    qs[i][tid] = (s < 65) ? qkv[base + (long long)s * 12288 + tid] : 0.f;
  }

  // scores: units = 9 i-pairs x 17 t-groups = 153
  const int up = tid / 17, tg = tid % 17;
  const int i0 = up * 2, t0 = tg * 4;
  const bool uval = (tid < 153);
  float acc[2][4] = {};
  for (int dc = 0; dc < 256; dc += 64) {
    __syncthreads();
    for (int idx = tid; idx < 65 * 64; idx += 256) {
      int t = idx >> 6, dd = idx & 63;
      Ks[t][dd] = qkv[base + (long long)t * 12288 + 256 + dc + dd];
    }
    __syncthreads();
    if (uval) {
#pragma unroll
      for (int d4 = 0; d4 < 64; d4 += 4) {
        float4 qa = *(const float4*)&qs[i0][dc + d4];
        float4 qb = *(const float4*)&qs[i0 + 1][dc + d4];
#pragma unroll
        for (int c = 0; c < 4; ++c) {
          float4 kv = *(const float4*)&Ks[t0 + c][d4];
          acc[0][c] += qa.x * kv.x + qa.y * kv.y + qa.z * kv.z + qa.w * kv.w;
          acc[1][c] += qb.x * kv.x + qb.y * kv.y + qb.z * kv.z + qb.w * kv.w;
        }
      }
    }
  }
  if (uval) {
#pragma unroll
    for (int ii = 0; ii < 2; ++ii) {
      int i = i0 + ii;
      if (i < AROWS && (s0 + i) < 65) {
#pragma unroll
        for (int c = 0; c < 4; ++c) {
          int t = t0 + c;
          if (t < 65) ps[i][t] = acc[ii][c] * 0.25f;
        }
      }
    }
  }
  __syncthreads();

  // softmax per row
  if (tid < AROWS && (s0 + tid) < 65) {
    float* row = ps[tid];
    float m = row[0];
    for (int t = 1; t < 65; ++t) m = fmaxf(m, row[t]);
    float sum = 0.f;
    for (int t = 0; t < 65; ++t) {
      float e = expf(row[t] - m);
      row[t] = e;
      sum += e;
    }
    float inv = 1.f / sum;
    for (int t = 0; t < 65; ++t) row[t] *= inv;
  }
  __syncthreads();

  // PV: thread owns column d=tid for all rows
  float oacc[AROWS];
#pragma unroll
  for (int i = 0; i < AROWS; ++i) oacc[i] = 0.f;
  const float* vp = qkv + base + 512 + tid;
  for (int t = 0; t < 65; ++t) {
    float vtd = vp[(long long)t * 12288];
#pragma unroll
    for (int i = 0; i < AROWS; ++i) oacc[i] += ps[i][t] * vtd;
  }
#pragma unroll
  for (int i = 0; i < AROWS; ++i) {
    int s = s0 + i;
    if (s < 65)
      O[(long long)(b * 65 + s) * 4096 + h * 256 + tid] = oacc[i];
  }
}

// ---------------- head GEMMs: split-K across wave-slices ----------------
// Block = 256 threads = KS k-slices x (256/KS) columns. Grid = (col tiles, M).
// B loads coalesced across columns; LDS reduce over k-slices.
template <int KS>
__global__ __launch_bounds__(256) void head_gemm2(
    const float* __restrict__ A, int lda, const float* __restrict__ B,
    const float* __restrict__ bias, float* __restrict__ C, int N, int K,
    int act) {
  constexpr int COLS = 256 / KS;
  __shared__ float red[KS][COLS];
  const int lane = threadIdx.x % COLS;
  const int ks = threadIdx.x / COLS;
  const int c = blockIdx.x * COLS + lane;
  const int r = blockIdx.y;
  const float* a = A + (long long)r * lda;
  float acc = 0.f;
  const int kc = K / KS;
  if (c < N) {
    const float* ap = a + ks * kc;
    const float* bp = B + (long long)(ks * kc) * N + c;
#pragma unroll 8
    for (int k = 0; k < kc; ++k) acc += ap[k] * bp[(long long)k * N];
  }
  red[ks][lane] = acc;
  __syncthreads();
  if (ks == 0 && c < N) {
    float v = bias[c];
#pragma unroll
    for (int s = 0; s < KS; ++s) v += red[s][lane];
    if (act) v = gelu_f(v);
    C[(long long)r * N + c] = v;
  }
}

extern "C" void kernel_launch(void* const* d_in, const int* in_sizes, int n_in,
                              void* d_out, int out_size, void* d_ws,
                              size_t ws_size, hipStream_t stream) {
  const float* x = (const float*)d_in[0];
  const float* conv_w = (const float*)d_in[1];
  const float* conv_b = (const float*)d_in[2];
  const float* cls = (const float*)d_in[3];
  const float* pos = (const float*)d_in[4];
  const float* Wqkv = (const float*)d_in[5];
  const float* bqkv = (const float*)d_in[6];
  const float* Wo = (const float*)d_in[7];
  const float* bo = (const float*)d_in[8];
  const float* ln1g = (const float*)d_in[9];
  const float* ln1b = (const float*)d_in[10];
  const float* ln2g = (const float*)d_in[11];
  const float* ln2b = (const float*)d_in[12];
  const float* Wm1 = (const float*)d_in[13];
  const float* bm1 = (const float*)d_in[14];
  const float* Wm2 = (const float*)d_in[15];
  const float* bm2 = (const float*)d_in[16];
  const float* Wh1 = (const float*)d_in[17];
  const float* bh1 = (const float*)d_in[18];
  const float* Wh2 = (const float*)d_in[19];
  const float* bh2 = (const float*)d_in[20];
  const float* Wh3 = (const float*)d_in[21];
  const float* bh3 = (const float*)d_in[22];
  float* out = (float*)d_out;

  float* ws = (float*)d_ws;
  float* tok = ws;                      // 520*256
  float* z = tok + 133120;              // 520*256
  float* y1 = z + 133120;               // 520*256
  float* qkvb = y1 + 133120;            // 520*12288
  float* Ob = qkvb + 6389760;           // 520*4096
  float* h1 = Ob + 2129920;             // 520*1024
  float* Pb = h1 + 532480;              // up to 16*520*256 / 4*520*1024
  float* h2 = Pb + 2129920;             // 8*256

  const int M = 520;

  embed_ln_kernel<<<520, 256, 0, stream>>>(x, conv_w, conv_b, cls, pos, ln1g,
                                           ln1b, tok, z);

  for (int l = 0; l < 24; ++l) {
    const float* Wq = Wqkv + (long long)l * 16 * 256 * 768;
    const float* bq = bqkv + l * 12288;
    const float* Wol = Wo + (long long)l * 4096 * 256;
    const float* bol = bo + l * 256;
    const float* W1 = Wm1 + (long long)l * 256 * 1024;
    const float* b1 = bm1 + l * 1024;
    const float* W2 = Wm2 + (long long)l * 1024 * 256;
    const float* b2 = bm2 + l * 256;

    // QKV: z(520x256) @ Wqkv_l -> qkvb(520x12288), head-grouped B
    gemm_f32<<<dim3(192, 9, 1), 256, 0, stream>>>(
        z, 256, Wq, 768, 768, 196608LL, qkvb, bq, nullptr, 0, M, 12288, 256, 1);

    // attention
    attn_kernel<<<dim3(4, 128), 256, 0, stream>>>(qkvb, Ob);

    // Wo: O(520x4096) @ Wo_l(4096x256), split-K=16 -> partials
    gemm_f32<<<dim3(4, 9, 16), 256, 0, stream>>>(
        Ob, 4096, Wol, 256, 1 << 30, 0LL, Pb, nullptr, nullptr, 0, M, 256,
        4096, 16);
    // y1 = sum + bo + tok ; z = LN2(y1)
    epilogue_kernel<<<520, 256, 0, stream>>>(Pb, 16, M, 256, bol, tok, y1, 0,
                                             ln2g + l * 256, ln2b + l * 256, z);

    // MLP1: z(520x256) @ W1(256x1024), split-K=4, gelu
    gemm_f32<<<dim3(16, 9, 4), 256, 0, stream>>>(
        z, 256, W1, 1024, 1 << 30, 0LL, Pb, nullptr, nullptr, 0, M, 1024, 256,
        4);
    epilogue_kernel<<<520, 256, 0, stream>>>(Pb, 4, M, 1024, b1, nullptr, h1, 1,
                                             nullptr, nullptr, nullptr);

    // MLP2: h1(520x1024) @ W2(1024x256), split-K=8, gelu, +y1 -> tok (new carry)
    gemm_f32<<<dim3(4, 9, 8), 256, 0, stream>>>(
        h1, 1024, W2, 256, 1 << 30, 0LL, Pb, nullptr, nullptr, 0, M, 256, 1024,
        8);
    const float* ng = (l < 23) ? ln1g + (l + 1) * 256 : nullptr;
    const float* nb = (l < 23) ? ln1b + (l + 1) * 256 : nullptr;
    float* nz = (l < 23) ? z : nullptr;
    epilogue_kernel<<<520, 256, 0, stream>>>(Pb, 8, M, 256, b2, y1, tok, 1, ng,
                                             nb, nz);
  }

  // classification head on cls token (row stride 65*256 picks s==0)
  // h1 = gelu(cls @ Wh1 + bh1): M=8, N=1024, K=256
  head_gemm2<4><<<dim3(16, 8), 256, 0, stream>>>(tok, 16640, Wh1, bh1, h1,
                                                 1024, 256, 1);
  // h2 = gelu(h1 @ Wh2 + bh2): M=8, N=256, K=1024
  head_gemm2<8><<<dim3(8, 8), 256, 0, stream>>>(h1, 1024, Wh2, bh2, h2, 256,
                                                1024, 1);
  // out = h2 @ Wh3 + bh3: M=8, N=1000, K=256
  head_gemm2<4><<<dim3(16, 8), 256, 0, stream>>>(h2, 256, Wh3, bh3, out, 1000,
                                                 256, 0);
}

// Round 5
// 3334.094 us; speedup vs baseline: 1.5079x; 1.3515x over previous
//
#include <hip/hip_runtime.h>
#include <hip/hip_bf16.h>

typedef __attribute__((ext_vector_type(8))) short short8;
typedef __attribute__((ext_vector_type(4))) float f32x4;

__device__ __forceinline__ float gelu_f(float x) {
  return 0.5f * x * (1.0f + erff(x * 0.70710678118654752440f));
}
__device__ __forceinline__ short f2bf(float f) {
  unsigned u = __float_as_uint(f);
  u += 0x7fffu + ((u >> 16) & 1u);
  return (short)(u >> 16);
}
__device__ __forceinline__ float bf2f(short s) {
  return __uint_as_float(((unsigned)(unsigned short)s) << 16);
}
// hi/lo bf16 split: v = hi + lo + O(2^-18 v)
__device__ __forceinline__ void split2(float v, short& h, short& l) {
  h = f2bf(v);
  l = f2bf(v - bf2f(h));
}
// swizzle a column index within its 64-elem group by row (involution)
__device__ __forceinline__ int swz(int col, int row) {
  return (col & ~63) | ((col & 63) ^ ((row & 7) << 3));
}

__device__ __forceinline__ float block_sum_256(float v, float* sb) {
#pragma unroll
  for (int o = 1; o < 64; o <<= 1) v += __shfl_xor(v, o, 64);
  if ((threadIdx.x & 63) == 0) sb[threadIdx.x >> 6] = v;
  __syncthreads();
  float r = sb[0] + sb[1] + sb[2] + sb[3];
  __syncthreads();
  return r;
}

// ------- weight transpose + convert: fp32 [K][N] -> bf16 hi/lo [N][K] swz --
__global__ __launch_bounds__(256) void convert_w(
    const float* __restrict__ in, short* __restrict__ outh,
    short* __restrict__ outl, int K, int N, int ldn, int group,
    long long gstride, long long in_lstride, long long out_lstride) {
  const float* inl = in + (long long)blockIdx.z * in_lstride;
  short* outhl = outh + (long long)blockIdx.z * out_lstride;
  short* outll = outl + (long long)blockIdx.z * out_lstride;
  const int n = blockIdx.x * 32 + (threadIdx.x & 31);
  const int seg = threadIdx.x >> 5;  // 0..7
  const int k0 = blockIdx.y * 256 + seg * 32;
  if (k0 >= K) return;
  const float* ip = inl + (long long)(n / group) * gstride + (n % group);
  float v[32];
#pragma unroll
  for (int i = 0; i < 32; ++i) v[i] = ip[(long long)(k0 + i) * ldn];
  const long long rowbase = (long long)n * K;
  const int grp = (n & 7) << 3;
#pragma unroll
  for (int j = 0; j < 4; ++j) {
    int k = k0 + j * 8;
    int kk = (k & ~63) | ((k & 63) ^ grp);
    short8 sh, sl;
#pragma unroll
    for (int i = 0; i < 8; ++i) {
      short h, L;
      split2(v[j * 8 + i], h, L);
      sh[i] = h;
      sl[i] = L;
    }
    *(short8*)(outhl + rowbase + kk) = sh;
    *(short8*)(outll + rowbase + kk) = sl;
  }
}

// ---------------- patch embed + pos emb + LN1(layer0) ----------------
__global__ __launch_bounds__(256) void embed_ln_kernel(
    const float* __restrict__ x, const float* __restrict__ cw,
    const float* __restrict__ cb, const float* __restrict__ cls,
    const float* __restrict__ pos, const float* __restrict__ g,
    const float* __restrict__ bb, float* __restrict__ tok,
    short* __restrict__ zh, short* __restrict__ zl) {
  __shared__ float sb[4];
  int r = blockIdx.x;  // b*65+s
  int b = r / 65, s = r % 65;
  int d = threadIdx.x;
  float val;
  if (s == 0) {
    val = cls[d];
  } else {
    int p = s - 1, pi = p >> 3, pj = p & 7;
    const float* xb = x + b * 3072 + pi * 4 * 32 + pj * 4;
    const float* w = cw + d * 48;
    float acc = cb[d];
#pragma unroll
    for (int c = 0; c < 3; ++c)
#pragma unroll
      for (int i = 0; i < 4; ++i)
#pragma unroll
        for (int j = 0; j < 4; ++j)
          acc += xb[c * 1024 + i * 32 + j] * w[c * 16 + i * 4 + j];
    val = acc;
  }
  val += pos[s * 256 + d];
  tok[r * 256 + d] = val;
  float mean = block_sum_256(val, sb) * (1.0f / 256.0f);
  float dv = val - mean;
  float var = block_sum_256(dv * dv, sb) * (1.0f / 256.0f);
  float z = dv * rsqrtf(var + 1e-5f) * g[d] + bb[d];
  short h, L;
  split2(z, h, L);
  zh[r * 256 + swz(d, r)] = h;
  zl[r * 256 + swz(d, r)] = L;
}

// -------- MFMA bf16x3 GEMM (fp32-quality), 128x128 tile, m97 structure ----
// A,B given as hi/lo bf16 pairs, rows swizzled. acc = AhBh + AhBl + AlBh.
// out32!=null: C=A@B(+bias) -> fp32.  else: fp32 partials to P[blockIdx.z].
__global__ __launch_bounds__(256) void gemm_x3(
    const short* __restrict__ Ah, const short* __restrict__ Al,
    const short* __restrict__ Bh, const short* __restrict__ Bl, int M, int N,
    int K, int kchunk, const float* __restrict__ bias,
    float* __restrict__ out32, float* __restrict__ P) {
  __shared__ short Ash[128 * 64];
  __shared__ short Asl[128 * 64];
  __shared__ short Bsh[128 * 64];
  __shared__ short Bsl[128 * 64];
  const int tid = threadIdx.x;
  const int w = tid >> 6, l = tid & 63;
  const int col0 = blockIdx.x * 128;
  const int row0 = blockIdx.y * 128;
  const int kbeg = blockIdx.z * kchunk;
  const int kend = kbeg + kchunk;
  const int wm = w >> 1, wn = w & 1;  // 2x2 waves of 64x64

  f32x4 acc[4][4];
#pragma unroll
  for (int i = 0; i < 4; ++i)
#pragma unroll
    for (int j = 0; j < 4; ++j) acc[i][j] = (f32x4)(0.f);

  const int srow = l >> 3;  // row within 8-row chunk
  const int sslot = l & 7;  // 16B slot

#define STAGE4(dst, src, rbase)                                            \
  {                                                                        \
    _Pragma("unroll") for (int i = 0; i < 4; ++i) {                        \
      int r = (w * 4 + i) * 8 + srow;                                      \
      const char* gp =                                                     \
          (const char*)(src + (size_t)(rbase + r) * K + k0) + sslot * 16;  \
      short* lp = dst + (w * 4 + i) * 512;                                 \
      __builtin_amdgcn_global_load_lds(                                    \
          (const __attribute__((address_space(1))) unsigned int*)gp,       \
          (__attribute__((address_space(3))) unsigned int*)lp, 16, 0, 0);  \
    }                                                                      \
  }

  for (int k0 = kbeg; k0 < kend; k0 += 64) {
    __syncthreads();
    STAGE4(Ash, Ah, row0)
    STAGE4(Asl, Al, row0)
    STAGE4(Bsh, Bh, col0)
    STAGE4(Bsl, Bl, col0)
    __syncthreads();
#pragma unroll
    for (int kc = 0; kc < 2; ++kc) {
      short8 ah[4], al[4], bh[4], bl[4];
#pragma unroll
      for (int mi = 0; mi < 4; ++mi) {
        int row = wm * 64 + mi * 16 + (l & 15);
        int slot = (kc * 4 + (l >> 4)) ^ (row & 7);
        ah[mi] = *(const short8*)&Ash[row * 64 + slot * 8];
        al[mi] = *(const short8*)&Asl[row * 64 + slot * 8];
      }
#pragma unroll
      for (int ni = 0; ni < 4; ++ni) {
        int row = wn * 64 + ni * 16 + (l & 15);
        int slot = (kc * 4 + (l >> 4)) ^ (row & 7);
        bh[ni] = *(const short8*)&Bsh[row * 64 + slot * 8];
        bl[ni] = *(const short8*)&Bsl[row * 64 + slot * 8];
      }
#pragma unroll
      for (int mi = 0; mi < 4; ++mi)
#pragma unroll
        for (int ni = 0; ni < 4; ++ni) {
          acc[mi][ni] = __builtin_amdgcn_mfma_f32_16x16x32_bf16(
              ah[mi], bh[ni], acc[mi][ni], 0, 0, 0);
          acc[mi][ni] = __builtin_amdgcn_mfma_f32_16x16x32_bf16(
              ah[mi], bl[ni], acc[mi][ni], 0, 0, 0);
          acc[mi][ni] = __builtin_amdgcn_mfma_f32_16x16x32_bf16(
              al[mi], bh[ni], acc[mi][ni], 0, 0, 0);
        }
    }
  }
#undef STAGE4

#pragma unroll
  for (int mi = 0; mi < 4; ++mi) {
#pragma unroll
    for (int ni = 0; ni < 4; ++ni) {
      int row = row0 + wm * 64 + mi * 16 + (l >> 4) * 4;
      int col = col0 + wn * 64 + ni * 16 + (l & 15);
      if (out32) {
        float bc = bias ? bias[col] : 0.f;
#pragma unroll
        for (int r = 0; r < 4; ++r)
          if (row + r < M)
            out32[(size_t)(row + r) * N + col] = acc[mi][ni][r] + bc;
      } else {
        float* Pz = P + (size_t)blockIdx.z * M * N;
#pragma unroll
        for (int r = 0; r < 4; ++r)
          if (row + r < M) Pz[(size_t)(row + r) * N + col] = acc[mi][ni][r];
      }
    }
  }
}

// ---------------- split-K reduce + bias + act + residual (+ LN) ----------
__global__ __launch_bounds__(256) void epilogue_kernel(
    const float* __restrict__ P, int nsplit, int M, int N,
    const float* __restrict__ bias, const float* __restrict__ res,
    float* __restrict__ out32, short* __restrict__ o16h,
    short* __restrict__ o16l, int act, const float* __restrict__ g,
    const float* __restrict__ bln, short* __restrict__ z16h,
    short* __restrict__ z16l) {
  __shared__ float sb[4];
  int r = blockIdx.x;
  float myval = 0.f;
  for (int c = threadIdx.x; c < N; c += 256) {
    float acc = 0.f;
    for (int s = 0; s < nsplit; ++s)
      acc += P[(long long)s * M * N + (long long)r * N + c];
    acc += bias[c];
    if (act) acc = gelu_f(acc);
    if (res) acc += res[(long long)r * N + c];
    if (out32) out32[(long long)r * N + c] = acc;
    if (o16h) {
      short h, L;
      split2(acc, h, L);
      o16h[(long long)r * N + swz(c, r)] = h;
      o16l[(long long)r * N + swz(c, r)] = L;
    }
    myval = acc;
  }
  if (z16h) {  // N==256 only
    float mean = block_sum_256(myval, sb) * (1.f / 256.f);
    float dv = myval - mean;
    float var = block_sum_256(dv * dv, sb) * (1.f / 256.f);
    float z = dv * rsqrtf(var + 1e-5f) * g[threadIdx.x] + bln[threadIdx.x];
    short h, L;
    split2(z, h, L);
    z16h[r * 256 + swz((int)threadIdx.x, r)] = h;
    z16l[r * 256 + swz((int)threadIdx.x, r)] = L;
  }
}

// ------- attention (fp32 qkv in, hi/lo bf16 out), 17 q-rows per block -----
#define AROWS 17
__global__ __launch_bounds__(256) void attn_kernel(const float* __restrict__ qkv,
                                                   short* __restrict__ Oh,
                                                   short* __restrict__ Ol) {
  __shared__ float qs[AROWS + 1][256];
  __shared__ float Ks[68][68];
  __shared__ float ps[AROWS][66];
  const int tid = threadIdx.x;
  const int s0 = blockIdx.x * AROWS;
  const int bh = blockIdx.y;
  const int b = bh >> 4, h = bh & 15;
  const long long base = (long long)(b * 65) * 12288 + h * 768;

#pragma unroll
  for (int i = 0; i < AROWS; ++i) {
    int s = s0 + i;
    qs[i][tid] = (s < 65) ? qkv[base + (long long)s * 12288 + tid] : 0.f;
  }

  const int up = tid / 17, tg = tid % 17;
  const int i0 = up * 2, t0 = tg * 4;
  const bool uval = (tid < 153);
  float acc[2][4] = {};
  for (int dc = 0; dc < 256; dc += 64) {
    __syncthreads();
    for (int idx = tid; idx < 65 * 64; idx += 256) {
      int t = idx >> 6, dd = idx & 63;
      Ks[t][dd] = qkv[base + (long long)t * 12288 + 256 + dc + dd];
    }
    __syncthreads();
    if (uval) {
#pragma unroll
      for (int d4 = 0; d4 < 64; d4 += 4) {
        float4 qa = *(const float4*)&qs[i0][dc + d4];
        float4 qb = *(const float4*)&qs[i0 + 1][dc + d4];
#pragma unroll
        for (int c = 0; c < 4; ++c) {
          float4 kv = *(const float4*)&Ks[t0 + c][d4];
          acc[0][c] += qa.x * kv.x + qa.y * kv.y + qa.z * kv.z + qa.w * kv.w;
          acc[1][c] += qb.x * kv.x + qb.y * kv.y + qb.z * kv.z + qb.w * kv.w;
        }
      }
    }
  }
  if (uval) {
#pragma unroll
    for (int ii = 0; ii < 2; ++ii) {
      int i = i0 + ii;
      if (i < AROWS && (s0 + i) < 65) {
#pragma unroll
        for (int c = 0; c < 4; ++c) {
          int t = t0 + c;
          if (t < 65) ps[i][t] = acc[ii][c] * 0.25f;
        }
      }
    }
  }
  __syncthreads();

  if (tid < AROWS && (s0 + tid) < 65) {
    float* row = ps[tid];
    float m = row[0];
    for (int t = 1; t < 65; ++t) m = fmaxf(m, row[t]);
    float sum = 0.f;
    for (int t = 0; t < 65; ++t) {
      float e = expf(row[t] - m);
      row[t] = e;
      sum += e;
    }
    float inv = 1.f / sum;
    for (int t = 0; t < 65; ++t) row[t] *= inv;
  }
  __syncthreads();

  float oacc[AROWS];
#pragma unroll
  for (int i = 0; i < AROWS; ++i) oacc[i] = 0.f;
  const float* vp = qkv + base + 512 + tid;
  for (int t = 0; t < 65; ++t) {
    float vtd = vp[(long long)t * 12288];
#pragma unroll
    for (int i = 0; i < AROWS; ++i) oacc[i] += ps[i][t] * vtd;
  }
#pragma unroll
  for (int i = 0; i < AROWS; ++i) {
    int s = s0 + i;
    if (s < 65) {
      int row = b * 65 + s;
      int col = h * 256 + ((tid & ~63) | ((tid & 63) ^ ((row & 7) << 3)));
      short hh, LL;
      split2(oacc[i], hh, LL);
      Oh[(long long)row * 4096 + col] = hh;
      Ol[(long long)row * 4096 + col] = LL;
    }
  }
}

// ---------------- head GEMMs (fp32, tiny) ----------------
template <int KS>
__global__ __launch_bounds__(256) void head_gemm2(
    const float* __restrict__ A, int lda, const float* __restrict__ B,
    const float* __restrict__ bias, float* __restrict__ C, int N, int K,
    int act) {
  constexpr int COLS = 256 / KS;
  __shared__ float red[KS][COLS];
  const int lane = threadIdx.x % COLS;
  const int ks = threadIdx.x / COLS;
  const int c = blockIdx.x * COLS + lane;
  const int r = blockIdx.y;
  const float* a = A + (long long)r * lda;
  float acc = 0.f;
  const int kc = K / KS;
  if (c < N) {
    const float* ap = a + ks * kc;
    const float* bp = B + (long long)(ks * kc) * N + c;
#pragma unroll 8
    for (int k = 0; k < kc; ++k) acc += ap[k] * bp[(long long)k * N];
  }
  red[ks][lane] = acc;
  __syncthreads();
  if (ks == 0 && c < N) {
    float v = bias[c];
#pragma unroll
    for (int s = 0; s < KS; ++s) v += red[s][lane];
    if (act) v = gelu_f(v);
    C[(long long)r * N + c] = v;
  }
}

extern "C" void kernel_launch(void* const* d_in, const int* in_sizes, int n_in,
                              void* d_out, int out_size, void* d_ws,
                              size_t ws_size, hipStream_t stream) {
  const float* x = (const float*)d_in[0];
  const float* conv_w = (const float*)d_in[1];
  const float* conv_b = (const float*)d_in[2];
  const float* cls = (const float*)d_in[3];
  const float* pos = (const float*)d_in[4];
  const float* Wqkv = (const float*)d_in[5];
  const float* bqkv = (const float*)d_in[6];
  const float* Wo = (const float*)d_in[7];
  const float* bo = (const float*)d_in[8];
  const float* ln1g = (const float*)d_in[9];
  const float* ln1b = (const float*)d_in[10];
  const float* ln2g = (const float*)d_in[11];
  const float* ln2b = (const float*)d_in[12];
  const float* Wm1 = (const float*)d_in[13];
  const float* bm1 = (const float*)d_in[14];
  const float* Wm2 = (const float*)d_in[15];
  const float* bm2 = (const float*)d_in[16];
  const float* Wh1 = (const float*)d_in[17];
  const float* bh1 = (const float*)d_in[18];
  const float* Wh2 = (const float*)d_in[19];
  const float* bh2 = (const float*)d_in[20];
  const float* Wh3 = (const float*)d_in[21];
  const float* bh3 = (const float*)d_in[22];
  float* out = (float*)d_out;

  // ---- workspace map (float units) -------------------------------------
  // tok 163840 | y1 163840 | Pb 2129920 (16x520x256) | qkvf 6389760
  // zh/zl 81920 ea | Oh/Ol 1310720 ea | h1h/h1l 327680 ea
  // hh1 8192 | hh2 2048 | Wqh/Wql 37748736 ea | Woh/Wol 12582912 ea
  // W1h/W1l 3145728 ea | W2h/W2l 3145728 ea     total ~502 MB
  float* ws = (float*)d_ws;
  float* tok = ws;
  float* y1 = ws + 163840;
  float* Pb = ws + 327680;
  float* qkvf = ws + 2457600;
  short* zh = (short*)(ws + 8847360);
  short* zl = (short*)(ws + 8929280);
  short* Oh = (short*)(ws + 9011200);
  short* Ol = (short*)(ws + 10321920);
  short* h1h = (short*)(ws + 11632640);
  short* h1l = (short*)(ws + 11960320);
  float* hh1 = ws + 12288000;
  float* hh2 = ws + 12296192;
  short* Wqh = (short*)(ws + 12298240);
  short* Wql = (short*)(ws + 50046976);
  short* Woh = (short*)(ws + 87795712);
  short* Wol_ = (short*)(ws + 100378624);
  short* W1h = (short*)(ws + 112961536);
  short* W1l = (short*)(ws + 116107264);
  short* W2h = (short*)(ws + 119252992);
  short* W2l = (short*)(ws + 122398720);

  const int M = 520;

  convert_w<<<dim3(384, 1, 24), 256, 0, stream>>>(
      Wqkv, Wqh, Wql, 256, 12288, 768, 768, 196608LL, 3145728LL, 3145728LL);
  convert_w<<<dim3(8, 16, 24), 256, 0, stream>>>(
      Wo, Woh, Wol_, 4096, 256, 256, 1 << 30, 0LL, 1048576LL, 1048576LL);
  convert_w<<<dim3(32, 1, 24), 256, 0, stream>>>(
      Wm1, W1h, W1l, 256, 1024, 1024, 1 << 30, 0LL, 262144LL, 262144LL);
  convert_w<<<dim3(8, 4, 24), 256, 0, stream>>>(
      Wm2, W2h, W2l, 1024, 256, 256, 1 << 30, 0LL, 262144LL, 262144LL);

  embed_ln_kernel<<<520, 256, 0, stream>>>(x, conv_w, conv_b, cls, pos, ln1g,
                                           ln1b, tok, zh, zl);

  for (int l = 0; l < 24; ++l) {
    const short* Wqhl = Wqh + (long long)l * 3145728;
    const short* Wqll = Wql + (long long)l * 3145728;
    const short* Wohl = Woh + (long long)l * 1048576;
    const short* Woll = Wol_ + (long long)l * 1048576;
    const short* W1hl = W1h + (long long)l * 262144;
    const short* W1ll = W1l + (long long)l * 262144;
    const short* W2hl = W2h + (long long)l * 262144;
    const short* W2ll = W2l + (long long)l * 262144;
    const float* bq = bqkv + l * 12288;
    const float* bol = bo + l * 256;
    const float* b1 = bm1 + l * 1024;
    const float* b2 = bm2 + l * 256;

    // QKV: z @ Wq -> qkvf fp32 (+bias)
    gemm_x3<<<dim3(96, 5, 1), 256, 0, stream>>>(zh, zl, Wqhl, Wqll, M, 12288,
                                                256, 256, bq, qkvf, nullptr);

    attn_kernel<<<dim3(4, 128), 256, 0, stream>>>(qkvf, Oh, Ol);

    // Wo: O(520x4096) @ Wo'(256x4096), split-K 16
    gemm_x3<<<dim3(2, 5, 16), 256, 0, stream>>>(Oh, Ol, Wohl, Woll, M, 256,
                                                4096, 256, nullptr, nullptr,
                                                Pb);
    epilogue_kernel<<<520, 256, 0, stream>>>(
        Pb, 16, M, 256, bol, tok, y1, nullptr, nullptr, 0, ln2g + l * 256,
        ln2b + l * 256, zh, zl);

    // MLP1: z @ Wm1'(1024x256), split-K 4, gelu -> h1 hi/lo
    gemm_x3<<<dim3(8, 5, 4), 256, 0, stream>>>(zh, zl, W1hl, W1ll, M, 1024,
                                               256, 64, nullptr, nullptr, Pb);
    epilogue_kernel<<<520, 256, 0, stream>>>(Pb, 4, M, 1024, b1, nullptr,
                                             nullptr, h1h, h1l, 1, nullptr,
                                             nullptr, nullptr, nullptr);

    // MLP2: h1 @ Wm2'(256x1024), split-K 16, gelu, +y1 -> tok
    gemm_x3<<<dim3(2, 5, 16), 256, 0, stream>>>(h1h, h1l, W2hl, W2ll, M, 256,
                                                1024, 64, nullptr, nullptr,
                                                Pb);
    const float* ng = (l < 23) ? ln1g + (l + 1) * 256 : nullptr;
    const float* nb = (l < 23) ? ln1b + (l + 1) * 256 : nullptr;
    short* nzh = (l < 23) ? zh : nullptr;
    short* nzl = (l < 23) ? zl : nullptr;
    epilogue_kernel<<<520, 256, 0, stream>>>(Pb, 16, M, 256, b2, y1, tok,
                                             nullptr, nullptr, 1, ng, nb, nzh,
                                             nzl);
  }

  head_gemm2<4><<<dim3(16, 8), 256, 0, stream>>>(tok, 16640, Wh1, bh1, hh1,
                                                 1024, 256, 1);
  head_gemm2<8><<<dim3(8, 8), 256, 0, stream>>>(hh1, 1024, Wh2, bh2, hh2, 256,
                                                1024, 1);
  head_gemm2<4><<<dim3(16, 8), 256, 0, stream>>>(hh2, 256, Wh3, bh3, out, 1000,
                                                 256, 0);
}